// Round 1
// baseline (272.573 us; speedup 1.0000x reference)
//
#include <hip/hip_runtime.h>

// Problem: x [B=8, T=16, C=64, H=64, W=64] fp32.
// out = x masked by per-batch top-K (K=2048 of N=4096) spatial sites,
// score[b,n] = mean_t sqrt(sum_c x[b,t,c,n]^2).
//
// Scores computed BIT-IDENTICALLY to numpy (sequential ascending-index
// accumulation, unfused mul/add, IEEE sqrt, *0.0625) -> kept set matches the
// reference exactly -> absmax 0 (verified R1-R4).
//
// R5 restructure: single HBM read of x.
//   k_sq_copy: read x once (nt load), write out=x (normal store -> L3-resident),
//              compute sq[b,t,n] (bit-exact).
//   k_select_fused: t-sum of sq fused into the verified bisection select
//              (no k_score kernel, no scores buffer in fast path).
//   k_zero: predicated scalar zero-stores to dropped sites (lines L3-resident).
// Old 3-kernel chain retained as ws-too-small fallback.

constexpr int NB = 8;
constexpr int NT = 16;
constexpr int NC = 64;
constexpr int NN = 4096;   // H*W
constexpr int KK = 2048;   // keep_k

typedef float vf4 __attribute__((ext_vector_type(4)));  // raw vec for nt builtins

// ---------------- Shared selection body (verified bisection w/ prefix skip) ---
// u[16] = score bits for sites n = tid*16 .. tid*16+15 (nonneg floats ->
// bit pattern is order-preserving). Emits mask[b*NN + ...].
__device__ __forceinline__ void topk_emit_mask(const unsigned* u, int b, int tid,
                                               float* __restrict__ mask) {
    __shared__ unsigned s_red[2][4];
    __shared__ unsigned s_scan[4];
    int wave = tid >> 6, lane = tid & 63;

    // --- block min/max of u -> common high-bit prefix ---
    unsigned lmin = u[0], lmax = u[0];
    #pragma unroll
    for (int k = 1; k < 16; ++k) {
        lmin = min(lmin, u[k]);
        lmax = max(lmax, u[k]);
    }
    #pragma unroll
    for (int off = 32; off > 0; off >>= 1) {
        lmin = min(lmin, (unsigned)__shfl_down((int)lmin, off, 64));
        lmax = max(lmax, (unsigned)__shfl_down((int)lmax, off, 64));
    }
    if (lane == 0) { s_red[0][wave] = lmin; s_red[1][wave] = lmax; }
    __syncthreads();
    unsigned umin = s_red[0][0], umax = s_red[1][0];
    #pragma unroll
    for (int w = 1; w < 4; ++w) {
        umin = min(umin, s_red[0][w]);
        umax = max(umax, s_red[1][w]);
    }
    __syncthreads();

    // --- bisection: max T with count(u >= T) >= KK (T = K-th largest bits) ---
    unsigned T;
    if (umax == umin) {
        T = umax;                      // all equal: pure tie case
    } else {
        int hb = 31 - __clz(umax ^ umin);      // hb <= 30 (scores >= 0)
        T = umax & ~((2u << hb) - 1);          // shared prefix, low bits 0
        for (int bit = hb; bit >= 0; --bit) {
            unsigned C = T | (1u << bit);
            int local = 0;
            #pragma unroll
            for (int k = 0; k < 16; ++k) local += (int)(u[k] >= C);
            #pragma unroll
            for (int off = 32; off > 0; off >>= 1)
                local += __shfl_down(local, off, 64);
            if (lane == 0) s_red[bit & 1][wave] = (unsigned)local;
            __syncthreads();
            int total = (int)s_red[bit & 1][0] + (int)s_red[bit & 1][1] +
                        (int)s_red[bit & 1][2] + (int)s_red[bit & 1][3];
            if (total >= KK) T = C;
            // alternating slot: entry reused two iters later, separated by a sync
        }
    }

    // --- cnt_gt = count(u > T) ---
    {
        int local = 0;
        #pragma unroll
        for (int k = 0; k < 16; ++k) local += (int)(u[k] > T);
        #pragma unroll
        for (int off = 32; off > 0; off >>= 1)
            local += __shfl_down(local, off, 64);
        __syncthreads();
        if (lane == 0) s_red[0][wave] = (unsigned)local;
    }
    __syncthreads();
    int cnt_gt = (int)s_red[0][0] + (int)s_red[0][1] +
                 (int)s_red[0][2] + (int)s_red[0][3];
    int keep_eq = KK - cnt_gt;         // #ties kept, ascending index (stable top_k)

    // --- exclusive prefix of equality counts across threads (ascending n) ---
    int lsum = 0;
    #pragma unroll
    for (int k = 0; k < 16; ++k) lsum += (int)(u[k] == T);
    int incl = lsum;
    #pragma unroll
    for (int off = 1; off < 64; off <<= 1) {
        int v = __shfl_up(incl, off, 64);
        if (lane >= off) incl += v;
    }
    if (lane == 63) s_scan[wave] = (unsigned)incl;
    __syncthreads();
    int woff = 0;
    for (int w = 0; w < wave; ++w) woff += (int)s_scan[w];
    int run = woff + incl - lsum;      // equal-count before this thread's chunk

    // --- emit mask ---
    #pragma unroll
    for (int k = 0; k < 4; ++k) {
        float4 m;
        float* mp = (float*)&m;
        #pragma unroll
        for (int j = 0; j < 4; ++j) {
            unsigned uv = u[4 * k + j];
            int e = (uv == T);
            mp[j] = ((uv > T) || (e && run < keep_eq)) ? 1.f : 0.f;
            run += e;
        }
        ((float4*)(mask + (size_t)b * NN))[tid * 4 + k] = m;
    }
}

// ---------------- Kernel A: sq[b,t,n] = sqrt(sum_c x^2), and out = x ----------
// Single HBM read of x. nt load (streaming, evict-first in L3) so the x stream
// does not displace the freshly written out lines; out stored normally so its
// lines are L3-resident for k_zero.
__global__ __launch_bounds__(256) void k_sq_copy(const float* __restrict__ x,
                                                 float* __restrict__ out,
                                                 float* __restrict__ sq) {
    int idx = blockIdx.x * 256 + threadIdx.x;          // over NB*NT*(NN/4)
    int n4 = idx & (NN / 4 - 1);
    int bt = idx >> 10;
    const vf4* xp = (const vf4*)(x + (size_t)bt * NC * NN) + n4;
    vf4* op = (vf4*)(out + (size_t)bt * NC * NN) + n4;
    float a0 = 0.f, a1 = 0.f, a2 = 0.f, a3 = 0.f;
    #pragma unroll 8
    for (int c = 0; c < NC; ++c) {
        vf4 v = __builtin_nontemporal_load(xp + c * (NN / 4));
        op[c * (NN / 4)] = v;                          // copy: out = x
        a0 = __fadd_rn(a0, __fmul_rn(v.x, v.x));
        a1 = __fadd_rn(a1, __fmul_rn(v.y, v.y));
        a2 = __fadd_rn(a2, __fmul_rn(v.z, v.z));
        a3 = __fadd_rn(a3, __fmul_rn(v.w, v.w));
    }
    float4 r;
    r.x = __fsqrt_rn(a0);
    r.y = __fsqrt_rn(a1);
    r.z = __fsqrt_rn(a2);
    r.w = __fsqrt_rn(a3);
    ((float4*)sq)[idx] = r;
}

// ---------------- Kernel B: fused t-sum + top-K select ------------------------
// score[b,n] = (sum_t sq[b,t,n]) * (1/16), sequential ascending t, bit-exact
// match to the old k_score. One block (256 thr) per batch.
__global__ __launch_bounds__(256) void k_select_fused(const float* __restrict__ sq,
                                                      float* __restrict__ mask) {
    int b = blockIdx.x;
    int tid = threadIdx.x;

    float acc[16];
    #pragma unroll
    for (int k = 0; k < 16; ++k) acc[k] = 0.f;
    const float* sb = sq + (size_t)b * NT * NN + tid * 16;
    #pragma unroll
    for (int t = 0; t < NT; ++t) {
        const float4* sp = (const float4*)(sb + (size_t)t * NN);
        #pragma unroll
        for (int k = 0; k < 4; ++k) {
            float4 v = sp[k];
            acc[4 * k + 0] = __fadd_rn(acc[4 * k + 0], v.x);
            acc[4 * k + 1] = __fadd_rn(acc[4 * k + 1], v.y);
            acc[4 * k + 2] = __fadd_rn(acc[4 * k + 2], v.z);
            acc[4 * k + 3] = __fadd_rn(acc[4 * k + 3], v.w);
        }
    }
    unsigned u[16];
    #pragma unroll
    for (int k = 0; k < 16; ++k)
        u[k] = __float_as_uint(__fmul_rn(acc[k], 0.0625f));

    topk_emit_mask(u, b, tid, mask);
}

// ---------------- Kernel C: zero dropped sites in out -------------------------
// out already holds x everywhere; write 0 to the ~50% dropped sites. Lines are
// L3-resident (just written by k_sq_copy) so the scattered 4B stores are
// absorbed by L2/L3.
__global__ __launch_bounds__(256) void k_zero(const float* __restrict__ mask,
                                              float* __restrict__ out) {
    int i = blockIdx.x * 256 + threadIdx.x;            // over total/4 = 2^23
    int b = i >> 20;                                   // NT*NC*NN/4 = 2^20 per batch
    int n4 = i & (NN / 4 - 1);
    float4 m = ((const float4*)mask)[b * (NN / 4) + n4];
    float* op = out + (size_t)i * 4;
    if (m.x == 0.f) op[0] = 0.f;
    if (m.y == 0.f) op[1] = 0.f;
    if (m.z == 0.f) op[2] = 0.f;
    if (m.w == 0.f) op[3] = 0.f;
}

// ================= Fallback path (ws too small for sq buffer) =================
__global__ __launch_bounds__(256) void k_score_fused(const float* __restrict__ x,
                                                     float* __restrict__ scores) {
    int idx = blockIdx.x * 256 + threadIdx.x;
    if (idx >= NB * NN) return;
    int b = idx >> 12;
    int n = idx & (NN - 1);
    const float* xb = x + (size_t)b * NT * NC * NN + n;
    float at = 0.f;
    for (int t = 0; t < NT; ++t) {
        float ac = 0.f;
        #pragma unroll 8
        for (int c = 0; c < NC; ++c) {
            float v = xb[(size_t)(t * NC + c) * NN];
            ac = __fadd_rn(ac, __fmul_rn(v, v));
        }
        at = __fadd_rn(at, __fsqrt_rn(ac));
    }
    scores[idx] = __fmul_rn(at, 0.0625f);
}

__global__ __launch_bounds__(256) void k_select3(const float* __restrict__ scores,
                                                 float* __restrict__ mask) {
    int b = blockIdx.x;
    int tid = threadIdx.x;
    unsigned u[16];
    const float4* sp = (const float4*)(scores + (size_t)b * NN);
    #pragma unroll
    for (int k = 0; k < 4; ++k) {
        float4 v = sp[tid * 4 + k];
        u[4 * k + 0] = __float_as_uint(v.x);
        u[4 * k + 1] = __float_as_uint(v.y);
        u[4 * k + 2] = __float_as_uint(v.z);
        u[4 * k + 3] = __float_as_uint(v.w);
    }
    topk_emit_mask(u, b, tid, mask);
}

__global__ __launch_bounds__(256) void k_apply(const float* __restrict__ x,
                                               const float* __restrict__ mask,
                                               float* __restrict__ out) {
    size_t i = (size_t)blockIdx.x * 256 + threadIdx.x; // over total/4
    int b = (int)(i >> 20);
    int n4 = (int)(i & (NN / 4 - 1));
    vf4 v = __builtin_nontemporal_load((const vf4*)x + i);
    float4 m = ((const float4*)mask)[b * (NN / 4) + n4];
    vf4 r;
    r.x = (m.x != 0.f) ? v.x : 0.f;
    r.y = (m.y != 0.f) ? v.y : 0.f;
    r.z = (m.z != 0.f) ? v.z : 0.f;
    r.w = (m.w != 0.f) ? v.w : 0.f;
    __builtin_nontemporal_store(r, (vf4*)out + i);
}

extern "C" void kernel_launch(void* const* d_in, const int* in_sizes, int n_in,
                              void* d_out, int out_size, void* d_ws, size_t ws_size,
                              hipStream_t stream) {
    const float* x = (const float*)d_in[0];
    float* out = (float*)d_out;
    float* ws = (float*)d_ws;

    // ws layout (floats): mask [NB*NN] | scores [NB*NN] | sq [NB*NT*NN]
    float* mask   = ws;
    float* scores = ws + NB * NN;
    float* sq     = ws + 2 * NB * NN;
    const size_t need_fast = (size_t)(2 * NB * NN + NB * NT * NN) * sizeof(float);
    const size_t need_slow = (size_t)(2 * NB * NN) * sizeof(float);

    if (ws_size >= need_fast) {
        // single-x-read path
        k_sq_copy<<<NB * NT * (NN / 4) / 256, 256, 0, stream>>>(x, out, sq);
        k_select_fused<<<NB, 256, 0, stream>>>(sq, mask);
        k_zero<<<NB * NT * NC * (NN / 4) / 256, 256, 0, stream>>>(mask, out);
    } else if (ws_size >= need_slow) {
        k_score_fused<<<(NB * NN + 255) / 256, 256, 0, stream>>>(x, scores);
        k_select3<<<NB, 256, 0, stream>>>(scores, mask);
        k_apply<<<NB * NT * NC * (NN / 4) / 256, 256, 0, stream>>>(x, mask, out);
    }
}

// Round 2
// 259.373 us; speedup vs baseline: 1.0509x; 1.0509x over previous
//
#include <hip/hip_runtime.h>

// Problem: x [B=8, T=16, C=64, H=64, W=64] fp32.
// out = x masked by per-batch top-K (K=2048 of N=4096) spatial sites,
// score[b,n] = mean_t sqrt(sum_c x[b,t,c,n]^2).
//
// Scores computed BIT-IDENTICALLY to numpy (sequential ascending-index
// accumulation, unfused mul/add, IEEE sqrt, *0.0625) -> kept set matches the
// reference exactly -> absmax 0 (verified R1-R5).
//
// R6: revert R5's copy+scatter-zero restructure (k_zero dirtied every out line
// -> full extra 134MB write-back, +15us). Back to the R4 3-read structure:
//   k_sq: plain (L3-allocating) loads of x, so k_apply's re-read hits L3.
//   k_select_fused: t-sum folded into the verified bisection select (this part
//     of R5 was correct and verified absmax 0) -> one fewer dispatch, no
//     scores round-trip.
//   k_apply: nt x load + nt out store (no RFO, no L3 churn of the x lines).

constexpr int NB = 8;
constexpr int NT = 16;
constexpr int NC = 64;
constexpr int NN = 4096;   // H*W
constexpr int KK = 2048;   // keep_k

typedef float vf4 __attribute__((ext_vector_type(4)));  // raw vec for nt builtins

// ---------------- Shared selection body (verified bisection w/ prefix skip) ---
// u[16] = score bits for sites n = tid*16 .. tid*16+15 (nonneg floats ->
// bit pattern is order-preserving). Emits mask[b*NN + ...].
__device__ __forceinline__ void topk_emit_mask(const unsigned* u, int b, int tid,
                                               float* __restrict__ mask) {
    __shared__ unsigned s_red[2][4];
    __shared__ unsigned s_scan[4];
    int wave = tid >> 6, lane = tid & 63;

    // --- block min/max of u -> common high-bit prefix ---
    unsigned lmin = u[0], lmax = u[0];
    #pragma unroll
    for (int k = 1; k < 16; ++k) {
        lmin = min(lmin, u[k]);
        lmax = max(lmax, u[k]);
    }
    #pragma unroll
    for (int off = 32; off > 0; off >>= 1) {
        lmin = min(lmin, (unsigned)__shfl_down((int)lmin, off, 64));
        lmax = max(lmax, (unsigned)__shfl_down((int)lmax, off, 64));
    }
    if (lane == 0) { s_red[0][wave] = lmin; s_red[1][wave] = lmax; }
    __syncthreads();
    unsigned umin = s_red[0][0], umax = s_red[1][0];
    #pragma unroll
    for (int w = 1; w < 4; ++w) {
        umin = min(umin, s_red[0][w]);
        umax = max(umax, s_red[1][w]);
    }
    __syncthreads();

    // --- bisection: max T with count(u >= T) >= KK (T = K-th largest bits) ---
    unsigned T;
    if (umax == umin) {
        T = umax;                      // all equal: pure tie case
    } else {
        int hb = 31 - __clz(umax ^ umin);      // hb <= 30 (scores >= 0)
        T = umax & ~((2u << hb) - 1);          // shared prefix, low bits 0
        for (int bit = hb; bit >= 0; --bit) {
            unsigned C = T | (1u << bit);
            int local = 0;
            #pragma unroll
            for (int k = 0; k < 16; ++k) local += (int)(u[k] >= C);
            #pragma unroll
            for (int off = 32; off > 0; off >>= 1)
                local += __shfl_down(local, off, 64);
            if (lane == 0) s_red[bit & 1][wave] = (unsigned)local;
            __syncthreads();
            int total = (int)s_red[bit & 1][0] + (int)s_red[bit & 1][1] +
                        (int)s_red[bit & 1][2] + (int)s_red[bit & 1][3];
            if (total >= KK) T = C;
            // alternating slot: entry reused two iters later, separated by a sync
        }
    }

    // --- cnt_gt = count(u > T) ---
    {
        int local = 0;
        #pragma unroll
        for (int k = 0; k < 16; ++k) local += (int)(u[k] > T);
        #pragma unroll
        for (int off = 32; off > 0; off >>= 1)
            local += __shfl_down(local, off, 64);
        __syncthreads();
        if (lane == 0) s_red[0][wave] = (unsigned)local;
    }
    __syncthreads();
    int cnt_gt = (int)s_red[0][0] + (int)s_red[0][1] +
                 (int)s_red[0][2] + (int)s_red[0][3];
    int keep_eq = KK - cnt_gt;         // #ties kept, ascending index (stable top_k)

    // --- exclusive prefix of equality counts across threads (ascending n) ---
    int lsum = 0;
    #pragma unroll
    for (int k = 0; k < 16; ++k) lsum += (int)(u[k] == T);
    int incl = lsum;
    #pragma unroll
    for (int off = 1; off < 64; off <<= 1) {
        int v = __shfl_up(incl, off, 64);
        if (lane >= off) incl += v;
    }
    if (lane == 63) s_scan[wave] = (unsigned)incl;
    __syncthreads();
    int woff = 0;
    for (int w = 0; w < wave; ++w) woff += (int)s_scan[w];
    int run = woff + incl - lsum;      // equal-count before this thread's chunk

    // --- emit mask ---
    #pragma unroll
    for (int k = 0; k < 4; ++k) {
        float4 m;
        float* mp = (float*)&m;
        #pragma unroll
        for (int j = 0; j < 4; ++j) {
            unsigned uv = u[4 * k + j];
            int e = (uv == T);
            mp[j] = ((uv > T) || (e && run < keep_eq)) ? 1.f : 0.f;
            run += e;
        }
        ((float4*)(mask + (size_t)b * NN))[tid * 4 + k] = m;
    }
}

// ---------------- Kernel A: sq[b,t,n] = sqrt(sum_c x[b,t,c,n]^2) ----------------
// Plain (L3-allocating) loads: x stays MALL-resident for k_apply's re-read.
__global__ __launch_bounds__(256) void k_sq(const float* __restrict__ x,
                                            float* __restrict__ sq) {
    int idx = blockIdx.x * 256 + threadIdx.x;          // over NB*NT*(NN/4)
    if (idx >= NB * NT * (NN / 4)) return;
    int n4 = (idx & (NN / 4 - 1));
    int bt = idx >> 10;
    const float4* xp = (const float4*)(x + (size_t)bt * NC * NN) + n4;
    float a0 = 0.f, a1 = 0.f, a2 = 0.f, a3 = 0.f;
    #pragma unroll 16
    for (int c = 0; c < NC; ++c) {
        float4 v = xp[c * (NN / 4)];
        a0 = __fadd_rn(a0, __fmul_rn(v.x, v.x));
        a1 = __fadd_rn(a1, __fmul_rn(v.y, v.y));
        a2 = __fadd_rn(a2, __fmul_rn(v.z, v.z));
        a3 = __fadd_rn(a3, __fmul_rn(v.w, v.w));
    }
    float4 r;
    r.x = __fsqrt_rn(a0);
    r.y = __fsqrt_rn(a1);
    r.z = __fsqrt_rn(a2);
    r.w = __fsqrt_rn(a3);
    ((float4*)sq)[idx] = r;
}

// ---------------- Kernel B: fused t-sum + top-K select ------------------------
// score[b,n] = (sum_t sq[b,t,n]) * (1/16), sequential ascending t, bit-exact
// match to the reference. One block (256 thr) per batch. sq is 2 MiB -> L2-hot.
__global__ __launch_bounds__(256) void k_select_fused(const float* __restrict__ sq,
                                                      float* __restrict__ mask) {
    int b = blockIdx.x;
    int tid = threadIdx.x;

    float acc[16];
    #pragma unroll
    for (int k = 0; k < 16; ++k) acc[k] = 0.f;
    const float* sb = sq + (size_t)b * NT * NN + tid * 16;
    #pragma unroll
    for (int t = 0; t < NT; ++t) {
        const float4* sp = (const float4*)(sb + (size_t)t * NN);
        #pragma unroll
        for (int k = 0; k < 4; ++k) {
            float4 v = sp[k];
            acc[4 * k + 0] = __fadd_rn(acc[4 * k + 0], v.x);
            acc[4 * k + 1] = __fadd_rn(acc[4 * k + 1], v.y);
            acc[4 * k + 2] = __fadd_rn(acc[4 * k + 2], v.z);
            acc[4 * k + 3] = __fadd_rn(acc[4 * k + 3], v.w);
        }
    }
    unsigned u[16];
    #pragma unroll
    for (int k = 0; k < 16; ++k)
        u[k] = __float_as_uint(__fmul_rn(acc[k], 0.0625f));

    topk_emit_mask(u, b, tid, mask);
}

// ---------------- Kernel C: out = mask ? x : 0 ----------------
// nt load (x re-read should hit L3; evict-first is fine) + nt store (no RFO,
// streaming write, doesn't displace x lines from L3).
__global__ __launch_bounds__(256) void k_apply(const float* __restrict__ x,
                                               const float* __restrict__ mask,
                                               float* __restrict__ out) {
    size_t i = (size_t)blockIdx.x * 256 + threadIdx.x; // over total/4
    int b = (int)(i >> 20);                            // NT*NC*NN/4 = 2^20 per batch
    int n4 = (int)(i & (NN / 4 - 1));
    vf4 v = __builtin_nontemporal_load((const vf4*)x + i);
    float4 m = ((const float4*)mask)[b * (NN / 4) + n4];
    vf4 r;
    r.x = (m.x != 0.f) ? v.x : 0.f;
    r.y = (m.y != 0.f) ? v.y : 0.f;
    r.z = (m.z != 0.f) ? v.z : 0.f;
    r.w = (m.w != 0.f) ? v.w : 0.f;
    __builtin_nontemporal_store(r, (vf4*)out + i);
}

// ================= Fallback path (ws too small for sq buffer) =================
__global__ __launch_bounds__(256) void k_score_fused(const float* __restrict__ x,
                                                     float* __restrict__ scores) {
    int idx = blockIdx.x * 256 + threadIdx.x;
    if (idx >= NB * NN) return;
    int b = idx >> 12;
    int n = idx & (NN - 1);
    const float* xb = x + (size_t)b * NT * NC * NN + n;
    float at = 0.f;
    for (int t = 0; t < NT; ++t) {
        float ac = 0.f;
        #pragma unroll 8
        for (int c = 0; c < NC; ++c) {
            float v = xb[(size_t)(t * NC + c) * NN];
            ac = __fadd_rn(ac, __fmul_rn(v, v));
        }
        at = __fadd_rn(at, __fsqrt_rn(ac));
    }
    scores[idx] = __fmul_rn(at, 0.0625f);
}

__global__ __launch_bounds__(256) void k_select3(const float* __restrict__ scores,
                                                 float* __restrict__ mask) {
    int b = blockIdx.x;
    int tid = threadIdx.x;
    unsigned u[16];
    const float4* sp = (const float4*)(scores + (size_t)b * NN);
    #pragma unroll
    for (int k = 0; k < 4; ++k) {
        float4 v = sp[tid * 4 + k];
        u[4 * k + 0] = __float_as_uint(v.x);
        u[4 * k + 1] = __float_as_uint(v.y);
        u[4 * k + 2] = __float_as_uint(v.z);
        u[4 * k + 3] = __float_as_uint(v.w);
    }
    topk_emit_mask(u, b, tid, mask);
}

extern "C" void kernel_launch(void* const* d_in, const int* in_sizes, int n_in,
                              void* d_out, int out_size, void* d_ws, size_t ws_size,
                              hipStream_t stream) {
    const float* x = (const float*)d_in[0];
    float* out = (float*)d_out;
    float* ws = (float*)d_ws;

    // ws layout (floats): mask [NB*NN] | scores [NB*NN] | sq [NB*NT*NN]
    float* mask   = ws;
    float* scores = ws + NB * NN;
    float* sq     = ws + 2 * NB * NN;
    const size_t need_fast = (size_t)(2 * NB * NN + NB * NT * NN) * sizeof(float);
    const size_t need_slow = (size_t)(2 * NB * NN) * sizeof(float);

    if (ws_size >= need_fast) {
        k_sq<<<(NB * NT * (NN / 4) + 255) / 256, 256, 0, stream>>>(x, sq);
        k_select_fused<<<NB, 256, 0, stream>>>(sq, mask);
        k_apply<<<NB * NT * NC * (NN / 4) / 256, 256, 0, stream>>>(x, mask, out);
    } else if (ws_size >= need_slow) {
        k_score_fused<<<(NB * NN + 255) / 256, 256, 0, stream>>>(x, scores);
        k_select3<<<NB, 256, 0, stream>>>(scores, mask);
        k_apply<<<NB * NT * NC * (NN / 4) / 256, 256, 0, stream>>>(x, mask, out);
    }
}